// Round 1
// baseline (243.436 us; speedup 1.0000x reference)
//
#include <hip/hip_runtime.h>

// One thread per 3-qubit state vector (8 complex amps).
// Layout: amp index i = q0*4 + q1*2 + q2.
// Circuit: H(q0), H(q1), RX(theta0,q0), RX(theta1,q1), CNOT(ctrl=q0, tgt=q2).
// Output: (B, 8, 2) float32, re/im interleaved.
__global__ __launch_bounds__(256) void circuit_kernel(
    const float* __restrict__ xr,
    const float* __restrict__ xi,
    const float* __restrict__ theta,
    float* __restrict__ out,
    int B)
{
    int t = blockIdx.x * blockDim.x + threadIdx.x;
    if (t >= B) return;

    const float k = 0.70710678118654752440f;  // 1/sqrt(2)
    float c0, s0, c1, s1;
    sincosf(theta[0] * 0.5f, &s0, &c0);
    sincosf(theta[1] * 0.5f, &s1, &c1);

    // Vectorized loads: 32 B per array per state.
    const float4* xr4 = reinterpret_cast<const float4*>(xr) + 2 * t;
    const float4* xi4 = reinterpret_cast<const float4*>(xi) + 2 * t;
    float4 ra = xr4[0], rb = xr4[1];
    float4 ia = xi4[0], ib = xi4[1];

    float r[8] = {ra.x, ra.y, ra.z, ra.w, rb.x, rb.y, rb.z, rb.w};
    float m[8] = {ia.x, ia.y, ia.z, ia.w, ib.x, ib.y, ib.z, ib.w};

    // --- Hadamard on qubit 0: pairs (i, i+4) ---
#pragma unroll
    for (int i = 0; i < 4; ++i) {
        float ar = r[i], am = m[i], br = r[i + 4], bm = m[i + 4];
        r[i]     = k * (ar + br);  m[i]     = k * (am + bm);
        r[i + 4] = k * (ar - br);  m[i + 4] = k * (am - bm);
    }
    // --- Hadamard on qubit 1: pairs (i, i+2), i in {0,1,4,5} ---
#pragma unroll
    for (int j = 0; j < 4; ++j) {
        int i = (j & 1) | ((j >> 1) << 2);  // 0,1,4,5
        float ar = r[i], am = m[i], br = r[i + 2], bm = m[i + 2];
        r[i]     = k * (ar + br);  m[i]     = k * (am + bm);
        r[i + 2] = k * (ar - br);  m[i + 2] = k * (am - bm);
    }
    // --- RX(theta0) on qubit 0: pairs (i, i+4) ---
    // a' = c*a - i s*b  -> re: c*ar + s*bi, im: c*ai - s*br
    // b' = -i s*a + c*b -> re: c*br + s*ai, im: c*bi - s*ar
#pragma unroll
    for (int i = 0; i < 4; ++i) {
        float ar = r[i], am = m[i], br = r[i + 4], bm = m[i + 4];
        r[i]     = c0 * ar + s0 * bm;
        m[i]     = c0 * am - s0 * br;
        r[i + 4] = c0 * br + s0 * am;
        m[i + 4] = c0 * bm - s0 * ar;
    }
    // --- RX(theta1) on qubit 1: pairs (i, i+2), i in {0,1,4,5} ---
#pragma unroll
    for (int j = 0; j < 4; ++j) {
        int i = (j & 1) | ((j >> 1) << 2);
        float ar = r[i], am = m[i], br = r[i + 2], bm = m[i + 2];
        r[i]     = c1 * ar + s1 * bm;
        m[i]     = c1 * am - s1 * br;
        r[i + 2] = c1 * br + s1 * am;
        m[i + 2] = c1 * bm - s1 * ar;
    }
    // --- CNOT(ctrl=q0, tgt=q2): swap 4<->5 and 6<->7 ---
    {
        float tr = r[4]; r[4] = r[5]; r[5] = tr;
        float tm = m[4]; m[4] = m[5]; m[5] = tm;
        tr = r[6]; r[6] = r[7]; r[7] = tr;
        tm = m[6]; m[6] = m[7]; m[7] = tm;
    }

    // Store interleaved (re, im): 64 B per state, four float4 stores.
    float4* o4 = reinterpret_cast<float4*>(out) + 4 * t;
    o4[0] = make_float4(r[0], m[0], r[1], m[1]);
    o4[1] = make_float4(r[2], m[2], r[3], m[3]);
    o4[2] = make_float4(r[4], m[4], r[5], m[5]);
    o4[3] = make_float4(r[6], m[6], r[7], m[7]);
}

extern "C" void kernel_launch(void* const* d_in, const int* in_sizes, int n_in,
                              void* d_out, int out_size, void* d_ws, size_t ws_size,
                              hipStream_t stream) {
    const float* xr    = (const float*)d_in[0];
    const float* xi    = (const float*)d_in[1];
    const float* theta = (const float*)d_in[2];
    // d_in[3] (angle) is dead in the reference.
    float* out = (float*)d_out;

    int B = in_sizes[0] / 8;
    int block = 256;
    int grid = (B + block - 1) / block;
    circuit_kernel<<<grid, block, 0, stream>>>(xr, xi, theta, out, B);
}

// Round 2
// 240.717 us; speedup vs baseline: 1.0113x; 1.0113x over previous
//
#include <hip/hip_runtime.h>

// Two threads per 3-qubit state vector. Thread u: state s = u>>1, half h = u&1,
// holding amps 4h..4h+3 (amp index = q0*4 + q1*2 + q2, so h == q0).
// Circuit: H(q0),H(q1),RX(t0,q0),RX(t1,q1),CNOT(q0->q2).
// Gates on distinct qubits commute -> apply fused M(q) = RX(q)*H per qubit:
//   M = k*[[c-is, c+is],[c-is, -(c+is)]]  =>  a' = p*a + q*b ; b' = p*a - q*b
//   with p = k(c-is), q = k(c+is), k = 1/sqrt(2).
// q0 gate couples the two threads of a state: each lane multiplies its half by
// (h ? q : p), exchanges via __shfl_xor(.,1) (adjacent-lane DPP), combines.
// q1 gate pairs (j, j+2) locally; CNOT (flip q2 when q0==1) is a local swap in
// the h==1 thread, folded into the store.
__global__ __launch_bounds__(256) void circuit_kernel(
    const float4* __restrict__ xr4,
    const float4* __restrict__ xi4,
    const float* __restrict__ theta,
    float4* __restrict__ o4,
    int N)  // N = 2*B half-states
{
    int u = blockIdx.x * blockDim.x + threadIdx.x;
    if (u >= N) return;
    const int h = u & 1;
    const float k = 0.70710678118654752440f;

    float c0, s0, c1, s1;
    __sincosf(theta[0] * 0.5f, &s0, &c0);
    __sincosf(theta[1] * 0.5f, &s1, &c1);

    // q0 multiplier for this lane: p for h=0, q for h=1
    const float mr = k * c0;
    const float mi = h ? (k * s0) : (-k * s0);

    // Perfectly coalesced loads: 16 B/lane, lane-contiguous.
    float4 fr = xr4[u];
    float4 fi = xi4[u];
    float ar[4] = {fr.x, fr.y, fr.z, fr.w};
    float ai[4] = {fi.x, fi.y, fi.z, fi.w};

    // --- fused H+RX on qubit 0 ---
    float lr[4], li[4], pr[4], pi[4];
#pragma unroll
    for (int j = 0; j < 4; ++j) {
        lr[j] = mr * ar[j] - mi * ai[j];
        li[j] = mr * ai[j] + mi * ar[j];
    }
#pragma unroll
    for (int j = 0; j < 4; ++j) {
        pr[j] = __shfl_xor(lr[j], 1, 64);
        pi[j] = __shfl_xor(li[j], 1, 64);
    }
#pragma unroll
    for (int j = 0; j < 4; ++j) {
        // h=0: local(p*a) + partner(q*b);  h=1: partner(p*a) - local(q*b)
        ar[j] = h ? (pr[j] - lr[j]) : (lr[j] + pr[j]);
        ai[j] = h ? (pi[j] - li[j]) : (li[j] + pi[j]);
    }

    // --- fused H+RX on qubit 1: pairs (j, j+2), local ---
    const float p1r = k * c1, p1i = -k * s1;
    const float q1r = k * c1, q1i = k * s1;
#pragma unroll
    for (int j = 0; j < 2; ++j) {
        float xr_ = p1r * ar[j]     - p1i * ai[j];
        float xi_ = p1r * ai[j]     + p1i * ar[j];
        float yr_ = q1r * ar[j + 2] - q1i * ai[j + 2];
        float yi_ = q1r * ai[j + 2] + q1i * ar[j + 2];
        ar[j]     = xr_ + yr_;  ai[j]     = xi_ + yi_;
        ar[j + 2] = xr_ - yr_;  ai[j + 2] = xi_ - yi_;
    }

    // --- CNOT (q0 ctrl, q2 tgt): h==1 swaps j0<->j1, j2<->j3; fold into store.
    int a = h ? 1 : 0, b = h ? 0 : 1, c = h ? 3 : 2, d = h ? 2 : 3;
    o4[2 * u]     = make_float4(ar[a], ai[a], ar[b], ai[b]);
    o4[2 * u + 1] = make_float4(ar[c], ai[c], ar[d], ai[d]);
}

extern "C" void kernel_launch(void* const* d_in, const int* in_sizes, int n_in,
                              void* d_out, int out_size, void* d_ws, size_t ws_size,
                              hipStream_t stream) {
    const float4* xr4  = (const float4*)d_in[0];
    const float4* xi4  = (const float4*)d_in[1];
    const float* theta = (const float*)d_in[2];
    float4* o4 = (float4*)d_out;

    int N = in_sizes[0] / 4;  // B*8 floats / 4 = 2B half-states
    int block = 256;
    int grid = (N + block - 1) / block;
    circuit_kernel<<<grid, block, 0, stream>>>(xr4, xi4, theta, o4, N);
}